// Round 1
// 835.750 us; speedup vs baseline: 1.1452x; 1.1452x over previous
//
#include <hip/hip_runtime.h>
#include <hip/hip_bf16.h>

typedef short bf16x8 __attribute__((ext_vector_type(8)));
typedef float f32x4  __attribute__((ext_vector_type(4)));

#define KD 1024

__device__ __forceinline__ short f2bf(float f) {
  unsigned u = __builtin_bit_cast(unsigned, f);
  u += 0x7fffu + ((u >> 16) & 1u);   // round-to-nearest-even
  return (short)(u >> 16);
}

// async global->LDS, 16B per lane; LDS dest = wave-uniform base + lane*16 (m104/m108)
__device__ __forceinline__ void gll16(const short* g, short* l) {
  __builtin_amdgcn_global_load_lds((const __attribute__((address_space(1))) unsigned int*)g,
                                   (__attribute__((address_space(3))) unsigned int*)l,
                                   16, 0, 0);
}

// ---------------------------------------------------------------------------
// Legacy 128x128 kernel — kept for MODE 0 (h_mean, M=64) and as runtime
// fallback if 128KB dynamic-LDS opt-in fails.
// C[M,N] = A[M,K] @ B[N,K]^T, bf16 inputs, K = N = 1024.
// MODE 0: out = C + bias[col]                  (fp32, rows guarded by M)
// MODE 1: tout[col*1024+row] = bf16(C)         (transposed bf16 store)
// MODE 2: out = C + cvec[ncv0+z]*kB + bcv      (fp32)
template <int MODE>
__global__ __launch_bounds__(256) void gemm_bt(
    const short* __restrict__ A, size_t a_bs,
    const short* __restrict__ B, size_t b_bs,
    float* __restrict__ out, size_t o_bs,
    short* __restrict__ tout, size_t t_bs,
    const float* __restrict__ kB, const float* __restrict__ bcv,
    const float* __restrict__ cvec, int ncv0,
    const float* __restrict__ bias, int M) {
  __shared__ short sA[128 * 32];
  __shared__ short sB[128 * 32];
  const int t = threadIdx.x;
  const int z = blockIdx.z;
  const short* Ab = A + (size_t)z * a_bs;
  const short* Bb = B + (size_t)z * b_bs;
  const int m0 = blockIdx.y * 128, n0 = blockIdx.x * 128;
  const int lane = t & 63, wv = t >> 6;
  const int wm = (wv >> 1) * 64, wn = (wv & 1) * 64;
  const int r16 = lane & 15, q = lane >> 4;

  const int srow = wv * 16 + (lane >> 2);
  const int skof = (lane & 3) * 8;
  short* lA0 = &sA[(wv * 16) * 32];
  short* lA1 = &sA[(64 + wv * 16) * 32];
  short* lB0 = &sB[(wv * 16) * 32];
  short* lB1 = &sB[(64 + wv * 16) * 32];
  const int ar0 = min(m0 + srow, M - 1);
  const int ar1 = min(m0 + 64 + srow, M - 1);
  const short* gA0 = Ab + (size_t)ar0 * KD + skof;
  const short* gA1 = Ab + (size_t)ar1 * KD + skof;
  const short* gB0 = Bb + (size_t)(n0 + srow) * KD + skof;
  const short* gB1 = Bb + (size_t)(n0 + 64 + srow) * KD + skof;

  f32x4 acc[4][4];
  const f32x4 zero4 = {0.f, 0.f, 0.f, 0.f};
#pragma unroll
  for (int i = 0; i < 4; ++i)
#pragma unroll
    for (int j = 0; j < 4; ++j) acc[i][j] = zero4;

  for (int k0 = 0; k0 < KD; k0 += 32) {
    __syncthreads();
    gll16(gA0 + k0, lA0);
    gll16(gA1 + k0, lA1);
    gll16(gB0 + k0, lB0);
    gll16(gB1 + k0, lB1);
    __syncthreads();

    bf16x8 af[4], bf[4];
#pragma unroll
    for (int i = 0; i < 4; ++i) {
      af[i] = *(const bf16x8*)&sA[(wm + i * 16 + r16) * 32 + q * 8];
      bf[i] = *(const bf16x8*)&sB[(wn + i * 16 + r16) * 32 + q * 8];
    }
#pragma unroll
    for (int mi = 0; mi < 4; ++mi)
#pragma unroll
      for (int ni = 0; ni < 4; ++ni)
        acc[mi][ni] = __builtin_amdgcn_mfma_f32_16x16x32_bf16(af[mi], bf[ni], acc[mi][ni], 0, 0, 0);
  }

  float cv = 0.f;
  if (MODE == 2) cv = cvec[ncv0 + z];
  float* ob = out ? out + (size_t)z * o_bs : nullptr;

#pragma unroll
  for (int mi = 0; mi < 4; ++mi) {
#pragma unroll
    for (int ni = 0; ni < 4; ++ni) {
      const int row0 = m0 + wm + mi * 16 + q * 4;
      const int col = n0 + wn + ni * 16 + r16;
      f32x4 a = acc[mi][ni];
      if (MODE == 0) {
        float bv = bias[col];
#pragma unroll
        for (int r = 0; r < 4; ++r)
          if (row0 + r < M) ob[(size_t)(row0 + r) * 1024 + col] = a[r] + bv;
      } else if (MODE == 1) {
        short4 s;
        s.x = f2bf(a[0]); s.y = f2bf(a[1]); s.z = f2bf(a[2]); s.w = f2bf(a[3]);
        *(short4*)(tout + (size_t)z * t_bs + (size_t)col * 1024 + row0) = s;
      } else {
#pragma unroll
        for (int r = 0; r < 4; ++r) {
          size_t idx = (size_t)(row0 + r) * 1024 + col;
          ob[idx] = a[r] + cv * kB[idx] + bcv[idx];
        }
      }
    }
  }
}

// ---------------------------------------------------------------------------
// 256x256 / BK=64 / 8-wave 4-phase-per-K-tile schedule (T2+T3+T4+T5).
// 128 KiB dynamic LDS: [Abuf0 | Abuf1 | Bbuf0 | Bbuf1], each 256x64 bf16.
// LDS reads are chunk^=(row&7) XOR-swizzled; global_load_lds writes linearly,
// so the inverse swizzle is folded into the per-lane GLOBAL source address
// (rule 21: linear dest + inverse-swz source + swz on read).
// Main loop never drains vmcnt: vmcnt(8) once per K-tile (next-next tile's
// 8 loads allowed in flight).
template <int MODE>
__global__ __launch_bounds__(512, 2) void gemm256(
    const short* __restrict__ A, size_t a_bs,
    const short* __restrict__ B, size_t b_bs,
    float* __restrict__ out, size_t o_bs,
    short* __restrict__ tout, size_t t_bs,
    const float* __restrict__ kB, const float* __restrict__ bcv,
    const float* __restrict__ cvec, int ncv0) {
  extern __shared__ short lds[];
  short* ldsB = lds + 32768;
  const int t = threadIdx.x;
  const int z = blockIdx.z;
  const short* Ab = A + (size_t)z * a_bs;
  const short* Bb = B + (size_t)z * b_bs;
  const int m0 = blockIdx.y * 256, n0 = blockIdx.x * 256;
  const int lane = t & 63, wv = t >> 6;
  const int wm = (wv >> 2) * 128, wn = (wv & 3) * 64;   // 2x4 wave grid, 128x64/wave
  const int r16 = lane & 15, q = lane >> 4;
  // swizzled read offsets (shorts) for k-step 0 / 1; row&7 == r16&7 for all frags
  const int sw0 = ((q ^ (r16 & 7)) << 3);
  const int sw1 = (((4 + q) ^ (r16 & 7)) << 3);

  // staging: round rr covers tile rows rr*64..rr*64+63; thread t -> row t>>3,
  // 16B chunk t&7, global column pre-swizzled by ^(row&7)
  const int trow = t >> 3;
  const int scol = (((t & 7) ^ (trow & 7)) << 3);
  const short* gAa = Ab + (size_t)(m0 + trow) * KD + scol;
  const short* gBa = Bb + (size_t)(n0 + trow) * KD + scol;
  short* lAw = lds + wv * 512;    // wave-uniform base; HW adds lane*16B
  short* lBw = ldsB + wv * 512;

#define STAGE_A(KT, H) { _Pragma("unroll") for (int r2 = 0; r2 < 2; ++r2) { \
    const int rr = (H) * 2 + r2; \
    gll16(gAa + (size_t)rr * (64 * KD) + (KT) * 64, lAw + ((KT) & 1) * 16384 + rr * 4096); } }
#define STAGE_B(KT, H) { _Pragma("unroll") for (int r2 = 0; r2 < 2; ++r2) { \
    const int rr = (H) * 2 + r2; \
    gll16(gBa + (size_t)rr * (64 * KD) + (KT) * 64, lBw + ((KT) & 1) * 16384 + rr * 4096); } }

  f32x4 acc[8][4];
#pragma unroll
  for (int i = 0; i < 8; ++i)
#pragma unroll
    for (int j = 0; j < 4; ++j) acc[i][j] = (f32x4){0.f, 0.f, 0.f, 0.f};

  // prologue: K-tiles 0 and 1 (8 loads each per thread)
  STAGE_A(0, 0); STAGE_A(0, 1); STAGE_B(0, 0); STAGE_B(0, 1);
  STAGE_A(1, 0); STAGE_A(1, 1); STAGE_B(1, 0); STAGE_B(1, 1);
  asm volatile("s_waitcnt vmcnt(8)" ::: "memory");   // tile 0 landed; tile 1 in flight
  __builtin_amdgcn_s_barrier();

  bf16x8 af[4][2];   // current m-half A frags
  bf16x8 bb[4][2];   // all 4 n-frags (kept across phases)

#define READ_A(MH) { _Pragma("unroll") for (int mq = 0; mq < 4; ++mq) { \
    const short* p = sAc + (wm + (MH) * 64 + mq * 16 + r16) * 64; \
    af[mq][0] = *(const bf16x8*)(p + sw0); \
    af[mq][1] = *(const bf16x8*)(p + sw1); } }
#define READ_B(NH) { _Pragma("unroll") for (int nq = 0; nq < 2; ++nq) { \
    const short* p = sBc + (wn + (NH) * 32 + nq * 16 + r16) * 64; \
    bb[(NH) * 2 + nq][0] = *(const bf16x8*)(p + sw0); \
    bb[(NH) * 2 + nq][1] = *(const bf16x8*)(p + sw1); } }
#define MFMA_Q(MH, NH) { _Pragma("unroll") for (int mq = 0; mq < 4; ++mq) \
    _Pragma("unroll") for (int nq = 0; nq < 2; ++nq) { \
      f32x4 c = acc[(MH) * 4 + mq][(NH) * 2 + nq]; \
      c = __builtin_amdgcn_mfma_f32_16x16x32_bf16(af[mq][0], bb[(NH) * 2 + nq][0], c, 0, 0, 0); \
      c = __builtin_amdgcn_mfma_f32_16x16x32_bf16(af[mq][1], bb[(NH) * 2 + nq][1], c, 0, 0, 0); \
      acc[(MH) * 4 + mq][(NH) * 2 + nq] = c; } }
#define BAR_IN() { asm volatile("" ::: "memory"); __builtin_amdgcn_s_barrier(); \
    asm volatile("s_waitcnt lgkmcnt(0)" ::: "memory"); \
    __builtin_amdgcn_sched_barrier(0); __builtin_amdgcn_s_setprio(1); }
#define BAR_OUT() { __builtin_amdgcn_s_setprio(0); asm volatile("" ::: "memory"); \
    __builtin_amdgcn_s_barrier(); }

  for (int g = 0; g < 16; ++g) {
    const short* sAc = lds + (g & 1) * 16384;
    const short* sBc = ldsB + (g & 1) * 16384;
    // P1: A-half0 (8 reads) + B n-frags 0-1 (4 reads)
    READ_A(0); READ_B(0);
    BAR_IN(); MFMA_Q(0, 0); BAR_OUT();
    // P2: B n-frags 2-3 (4 reads)
    READ_B(1);
    BAR_IN(); MFMA_Q(0, 1); BAR_OUT();
    // P3: A-half1 (8 reads); B-region of this buffer fully consumed ->
    //     stage B of tile g+2 into it (issued after P2's barrier: safe)
    READ_A(1);
    if (g <= 13) { STAGE_B(g + 2, 0); STAGE_B(g + 2, 1); }
    BAR_IN(); MFMA_Q(1, 0); BAR_OUT();
    // P4: A-region consumed -> stage A of tile g+2; counted vmcnt(8):
    //     tile g+1 guaranteed landed, tile g+2's 8 loads stay in flight
    if (g <= 13) { STAGE_A(g + 2, 0); STAGE_A(g + 2, 1); }
    asm volatile("" ::: "memory");
    __builtin_amdgcn_s_barrier();
    __builtin_amdgcn_s_setprio(1);
    MFMA_Q(1, 1);
    __builtin_amdgcn_s_setprio(0);
    asm volatile("" ::: "memory");
    if (g <= 13) { asm volatile("s_waitcnt vmcnt(8)" ::: "memory"); }
    else         { asm volatile("s_waitcnt vmcnt(0)" ::: "memory"); }
    __builtin_amdgcn_s_barrier();
  }
#undef STAGE_A
#undef STAGE_B
#undef READ_A
#undef READ_B
#undef MFMA_Q
#undef BAR_IN
#undef BAR_OUT

  float cv = 0.f;
  if (MODE == 2) cv = cvec[ncv0 + z];
  float* ob = out ? out + (size_t)z * o_bs : nullptr;

#pragma unroll
  for (int me = 0; me < 8; ++me) {
#pragma unroll
    for (int ne = 0; ne < 4; ++ne) {
      const int row0 = m0 + wm + me * 16 + q * 4;
      const int col = n0 + wn + ne * 16 + r16;
      f32x4 a = acc[me][ne];
      if (MODE == 1) {
        short4 s;
        s.x = f2bf(a[0]); s.y = f2bf(a[1]); s.z = f2bf(a[2]); s.w = f2bf(a[3]);
        *(short4*)(tout + (size_t)z * t_bs + (size_t)col * 1024 + row0) = s;
      } else {
#pragma unroll
        for (int r = 0; r < 4; ++r) {
          size_t idx = (size_t)(row0 + r) * 1024 + col;
          ob[idx] = a[r] + cv * kB[idx] + bcv[idx];
        }
      }
    }
  }
}

// Fused: abf = bf16(a_cov);  c[n] += sum_ij a_cov[n,i,j]*kA[i,j] + a_mean[n]^T kA a_mean[n]
__global__ __launch_bounds__(256) void conv_acov(const float* __restrict__ a_cov,
                                                 const float* __restrict__ a_mean,
                                                 const float* __restrict__ kA,
                                                 short* __restrict__ abf,
                                                 float* __restrict__ c) {
  const int n = blockIdx.x, ch = blockIdx.y, t = threadIdx.x;
  __shared__ float sm[1024];
  for (int j = t; j < 1024; j += 256) sm[j] = a_mean[n * 1024 + j];
  __syncthreads();
  const float4 amv = ((const float4*)sm)[t];
  const size_t cb = ((size_t)n << 20);
  float acc = 0.f;
  for (int i = ch * 64; i < ch * 64 + 64; ++i) {
    float4 Av = ((const float4*)(kA + ((size_t)i << 10)))[t];
    float4 Cv = ((const float4*)(a_cov + cb + ((size_t)i << 10)))[t];
    short4 s;
    s.x = f2bf(Cv.x); s.y = f2bf(Cv.y); s.z = f2bf(Cv.z); s.w = f2bf(Cv.w);
    *(short4*)(abf + cb + ((size_t)i << 10) + t * 4) = s;
    acc += Av.x * Cv.x + Av.y * Cv.y + Av.z * Cv.z + Av.w * Cv.w;
    acc += sm[i] * (Av.x * amv.x + Av.y * amv.y + Av.z * amv.z + Av.w * amv.w);
  }
#pragma unroll
  for (int off = 32; off > 0; off >>= 1) acc += __shfl_down(acc, off);
  __shared__ float red[4];
  if ((t & 63) == 0) red[t >> 6] = acc;
  __syncthreads();
  if (t == 0) atomicAdd(&c[n], red[0] + red[1] + red[2] + red[3]);
}

// generic f32 -> bf16, float4 granularity; n4 = n/4
__global__ __launch_bounds__(256) void convf(const float* __restrict__ src,
                                             short* __restrict__ dst, int n4) {
  int i = blockIdx.x * 256 + threadIdx.x;
  if (i < n4) {
    float4 v = ((const float4*)src)[i];
    short4 s;
    s.x = f2bf(v.x); s.y = f2bf(v.y); s.z = f2bf(v.z); s.w = f2bf(v.w);
    ((short4*)dst)[i] = s;
  }
}

extern "C" void kernel_launch(void* const* d_in, const int* in_sizes, int n_in,
                              void* d_out, int out_size, void* d_ws, size_t ws_size,
                              hipStream_t stream) {
  const float* a_mean = (const float*)d_in[0];
  const float* a_cov  = (const float*)d_in[1];
  const float* weight = (const float*)d_in[2];
  const float* bias   = (const float*)d_in[3];
  const float* kA     = (const float*)d_in[4];
  const float* kB     = (const float*)d_in[5];
  const float* b_cov  = (const float*)d_in[6];
  float* h_mean = (float*)d_out;
  float* h_cov  = h_mean + (size_t)64 * 1024;

  const size_t SLICE = (size_t)1 << 20;          // elems per batch slice (1024*1024)
  float* cvec = (float*)d_ws;
  short* Wbf  = (short*)((char*)d_ws + 4096);    // 2 MB
  short* ambf = Wbf + SLICE;                     // 128 KB
  char*  p    = (char*)(ambf + 65536);
  const size_t need_big = (size_t)((char*)p - (char*)d_ws) + 4 * SLICE * 64; // abf + Tt
  const bool big = ws_size >= need_big;

  short* abf, *Tt;
  if (big) {
    abf = (short*)p;
    Tt  = abf + 64 * SLICE;
  } else {
    abf = (short*)h_cov;                         // lower 128 MB of h_cov region
    Tt  = (short*)(h_cov + 64 * SLICE / 2);      // upper 128 MB
  }

  // one-time opt-in to 128 KiB dynamic LDS for the 256^2 kernels
  static int use256 = -1;
  if (use256 < 0) {
    auto k1 = gemm256<1>;
    auto k2 = gemm256<2>;
    bool ok1 = hipFuncSetAttribute(reinterpret_cast<const void*>(k1),
                                   hipFuncAttributeMaxDynamicSharedMemorySize, 131072) == hipSuccess;
    bool ok2 = hipFuncSetAttribute(reinterpret_cast<const void*>(k2),
                                   hipFuncAttributeMaxDynamicSharedMemorySize, 131072) == hipSuccess;
    use256 = (ok1 && ok2) ? 1 : 0;
  }

  hipMemsetAsync(cvec, 0, 64 * sizeof(float), stream);
  convf<<<dim3(1024), 256, 0, stream>>>(weight, Wbf, 262144);
  convf<<<dim3(64), 256, 0, stream>>>(a_mean, ambf, 16384);
  conv_acov<<<dim3(64, 16), 256, 0, stream>>>(a_cov, a_mean, kA, abf, cvec);

  // pass 1: Tt[n][l,i] = bf16( (a_cov[n] @ W^T)[i,l] )
  if (use256) {
    gemm256<1><<<dim3(4, 4, 64), 512, 131072, stream>>>(
        abf, SLICE, Wbf, 0, nullptr, 0, Tt, SLICE,
        nullptr, nullptr, nullptr, 0);
  } else {
    gemm_bt<1><<<dim3(8, 8, 64), 256, 0, stream>>>(
        abf, SLICE, Wbf, 0, nullptr, 0, Tt, SLICE,
        nullptr, nullptr, nullptr, 0, nullptr, 1024);
  }

  // h_mean = a_mean @ W^T + bias (M=64, clamped rows + guarded store)
  gemm_bt<0><<<dim3(8, 1, 1), 256, 0, stream>>>(
      ambf, 0, Wbf, 0, h_mean, 0, nullptr, 0,
      nullptr, nullptr, nullptr, 0, bias, 64);

  if (big) {
    // pass 2: h_cov[n] = W @ T[n] + c[n]*kB + b_cov
    if (use256) {
      gemm256<2><<<dim3(4, 4, 64), 512, 131072, stream>>>(
          Wbf, 0, Tt, SLICE, h_cov, SLICE, nullptr, 0,
          kB, b_cov, cvec, 0);
    } else {
      gemm_bt<2><<<dim3(8, 8, 64), 256, 0, stream>>>(
          Wbf, 0, Tt, SLICE, h_cov, SLICE, nullptr, 0,
          kB, b_cov, cvec, 0, nullptr, 1024);
    }
  } else {
    // In-place: h_cov[n] write clobbers Tt[m], m in {2n-64, 2n-63}.
    // Increasing windows keep clobbered m strictly below the window start.
    short* T63 = ambf + 65536;                   // 2 MB scratch in ws
    hipMemcpyAsync(T63, Tt + 63 * SLICE, SLICE * 2, hipMemcpyDeviceToDevice, stream);
    const int st[6] = {0, 32, 48, 56, 60, 62};
    const int ln[6] = {32, 16, 8, 4, 2, 1};
    for (int w = 0; w < 6; ++w) {
      if (use256) {
        gemm256<2><<<dim3(4, 4, ln[w]), 512, 131072, stream>>>(
            Wbf, 0, Tt + (size_t)st[w] * SLICE, SLICE,
            h_cov + (size_t)st[w] * SLICE, SLICE, nullptr, 0,
            kB, b_cov, cvec, st[w]);
      } else {
        gemm_bt<2><<<dim3(8, 8, ln[w]), 256, 0, stream>>>(
            Wbf, 0, Tt + (size_t)st[w] * SLICE, SLICE,
            h_cov + (size_t)st[w] * SLICE, SLICE, nullptr, 0,
            kB, b_cov, cvec, st[w], nullptr, 1024);
      }
    }
    if (use256) {
      gemm256<2><<<dim3(4, 4, 1), 512, 131072, stream>>>(
          Wbf, 0, T63, 0, h_cov + (size_t)63 * SLICE, 0, nullptr, 0,
          kB, b_cov, cvec, 63);
    } else {
      gemm_bt<2><<<dim3(8, 8, 1), 256, 0, stream>>>(
          Wbf, 0, T63, 0, h_cov + (size_t)63 * SLICE, 0, nullptr, 0,
          kB, b_cov, cvec, 63, nullptr, 1024);
    }
  }
}

// Round 2
// 811.211 us; speedup vs baseline: 1.1798x; 1.0302x over previous
//
#include <hip/hip_runtime.h>
#include <hip/hip_bf16.h>

typedef short bf16x8 __attribute__((ext_vector_type(8)));
typedef float f32x4  __attribute__((ext_vector_type(4)));

#define KD 1024

__device__ __forceinline__ short f2bf(float f) {
  unsigned u = __builtin_bit_cast(unsigned, f);
  u += 0x7fffu + ((u >> 16) & 1u);   // round-to-nearest-even
  return (short)(u >> 16);
}

// async global->LDS, 16B per lane; LDS dest = wave-uniform base + lane*16 (m104/m108)
__device__ __forceinline__ void gll16(const short* g, short* l) {
  __builtin_amdgcn_global_load_lds((const __attribute__((address_space(1))) unsigned int*)g,
                                   (__attribute__((address_space(3))) unsigned int*)l,
                                   16, 0, 0);
}

// ---------------------------------------------------------------------------
// Legacy 128x128 kernel — kept for MODE 0 (h_mean, M=64) and as runtime
// fallback if 128KB dynamic-LDS opt-in fails.
template <int MODE>
__global__ __launch_bounds__(256) void gemm_bt(
    const short* __restrict__ A, size_t a_bs,
    const short* __restrict__ B, size_t b_bs,
    float* __restrict__ out, size_t o_bs,
    short* __restrict__ tout, size_t t_bs,
    const float* __restrict__ kB, const float* __restrict__ bcv,
    const float* __restrict__ cvec, int ncv0,
    const float* __restrict__ bias, int M) {
  __shared__ short sA[128 * 32];
  __shared__ short sB[128 * 32];
  const int t = threadIdx.x;
  const int z = blockIdx.z;
  const short* Ab = A + (size_t)z * a_bs;
  const short* Bb = B + (size_t)z * b_bs;
  const int m0 = blockIdx.y * 128, n0 = blockIdx.x * 128;
  const int lane = t & 63, wv = t >> 6;
  const int wm = (wv >> 1) * 64, wn = (wv & 1) * 64;
  const int r16 = lane & 15, q = lane >> 4;

  const int srow = wv * 16 + (lane >> 2);
  const int skof = (lane & 3) * 8;
  short* lA0 = &sA[(wv * 16) * 32];
  short* lA1 = &sA[(64 + wv * 16) * 32];
  short* lB0 = &sB[(wv * 16) * 32];
  short* lB1 = &sB[(64 + wv * 16) * 32];
  const int ar0 = min(m0 + srow, M - 1);
  const int ar1 = min(m0 + 64 + srow, M - 1);
  const short* gA0 = Ab + (size_t)ar0 * KD + skof;
  const short* gA1 = Ab + (size_t)ar1 * KD + skof;
  const short* gB0 = Bb + (size_t)(n0 + srow) * KD + skof;
  const short* gB1 = Bb + (size_t)(n0 + 64 + srow) * KD + skof;

  f32x4 acc[4][4];
  const f32x4 zero4 = {0.f, 0.f, 0.f, 0.f};
#pragma unroll
  for (int i = 0; i < 4; ++i)
#pragma unroll
    for (int j = 0; j < 4; ++j) acc[i][j] = zero4;

  for (int k0 = 0; k0 < KD; k0 += 32) {
    __syncthreads();
    gll16(gA0 + k0, lA0);
    gll16(gA1 + k0, lA1);
    gll16(gB0 + k0, lB0);
    gll16(gB1 + k0, lB1);
    __syncthreads();

    bf16x8 af[4], bf[4];
#pragma unroll
    for (int i = 0; i < 4; ++i) {
      af[i] = *(const bf16x8*)&sA[(wm + i * 16 + r16) * 32 + q * 8];
      bf[i] = *(const bf16x8*)&sB[(wn + i * 16 + r16) * 32 + q * 8];
    }
#pragma unroll
    for (int mi = 0; mi < 4; ++mi)
#pragma unroll
      for (int ni = 0; ni < 4; ++ni)
        acc[mi][ni] = __builtin_amdgcn_mfma_f32_16x16x32_bf16(af[mi], bf[ni], acc[mi][ni], 0, 0, 0);
  }

  float cv = 0.f;
  if (MODE == 2) cv = cvec[ncv0 + z];
  float* ob = out ? out + (size_t)z * o_bs : nullptr;

#pragma unroll
  for (int mi = 0; mi < 4; ++mi) {
#pragma unroll
    for (int ni = 0; ni < 4; ++ni) {
      const int row0 = m0 + wm + mi * 16 + q * 4;
      const int col = n0 + wn + ni * 16 + r16;
      f32x4 a = acc[mi][ni];
      if (MODE == 0) {
        float bv = bias[col];
#pragma unroll
        for (int r = 0; r < 4; ++r)
          if (row0 + r < M) ob[(size_t)(row0 + r) * 1024 + col] = a[r] + bv;
      } else if (MODE == 1) {
        short4 s;
        s.x = f2bf(a[0]); s.y = f2bf(a[1]); s.z = f2bf(a[2]); s.w = f2bf(a[3]);
        *(short4*)(tout + (size_t)z * t_bs + (size_t)col * 1024 + row0) = s;
      } else {
#pragma unroll
        for (int r = 0; r < 4; ++r) {
          size_t idx = (size_t)(row0 + r) * 1024 + col;
          ob[idx] = a[r] + cv * kB[idx] + bcv[idx];
        }
      }
    }
  }
}

// ---------------------------------------------------------------------------
// 256x256 / BK=64 / 8-wave pipelined-quadrant schedule.
// Per K-tile: 4 MFMA quadrants; ds_reads for quadrant q+1 issued during
// quadrant q (counted lgkm waits emitted by compiler -> read-drain overlaps
// MFMA). Only TWO barriers per K-tile (P3: B-region reuse + P4: publish
// next buffer / A-region reuse). vmcnt counted (4), never 0 in steady state.
// LDS reads chunk^=(row&7) swizzled; inverse swizzle folded into global
// source addresses (rule 21), dest linear for global_load_lds.
template <int MODE>
__global__ __launch_bounds__(512, 2) void gemm256(
    const short* __restrict__ A, size_t a_bs,
    const short* __restrict__ B, size_t b_bs,
    float* __restrict__ out, size_t o_bs,
    short* __restrict__ tout, size_t t_bs,
    const float* __restrict__ kB, const float* __restrict__ bcv,
    const float* __restrict__ cvec, int ncv0) {
  extern __shared__ short lds[];
  short* ldsB = lds + 32768;
  const int t = threadIdx.x;
  const int z = blockIdx.z;
  const short* Ab = A + (size_t)z * a_bs;
  const short* Bb = B + (size_t)z * b_bs;
  const int m0 = blockIdx.y * 256, n0 = blockIdx.x * 256;
  const int lane = t & 63, wv = t >> 6;
  const int wm = (wv >> 2) * 128, wn = (wv & 3) * 64;   // 2x4 wave grid, 128x64/wave
  const int r16 = lane & 15, q = lane >> 4;
  const int sw0 = ((q ^ (r16 & 7)) << 3);
  const int sw1 = (((4 + q) ^ (r16 & 7)) << 3);

  const int trow = t >> 3;
  const int scol = (((t & 7) ^ (trow & 7)) << 3);
  const short* gAa = Ab + (size_t)(m0 + trow) * KD + scol;
  const short* gBa = Bb + (size_t)(n0 + trow) * KD + scol;
  short* lAw = lds + wv * 512;    // wave-uniform base; HW adds lane*16B
  short* lBw = ldsB + wv * 512;

#define STAGE_A(KT) { _Pragma("unroll") for (int rr = 0; rr < 4; ++rr) \
    gll16(gAa + (size_t)rr * (64 * KD) + (KT) * 64, lAw + ((KT) & 1) * 16384 + rr * 4096); }
#define STAGE_B(KT) { _Pragma("unroll") for (int rr = 0; rr < 4; ++rr) \
    gll16(gBa + (size_t)rr * (64 * KD) + (KT) * 64, lBw + ((KT) & 1) * 16384 + rr * 4096); }
#define RD_A(DST, BASE, MH) { _Pragma("unroll") for (int mq = 0; mq < 4; ++mq) { \
    const short* p_ = (BASE) + (wm + (MH) * 64 + mq * 16 + r16) * 64; \
    DST[mq][0] = *(const bf16x8*)(p_ + sw0); \
    DST[mq][1] = *(const bf16x8*)(p_ + sw1); } }
#define RD_B(DST, BASE, NH) { _Pragma("unroll") for (int nq = 0; nq < 2; ++nq) { \
    const short* p_ = (BASE) + (wn + (NH) * 32 + nq * 16 + r16) * 64; \
    DST[nq][0] = *(const bf16x8*)(p_ + sw0); \
    DST[nq][1] = *(const bf16x8*)(p_ + sw1); } }
#define QUAD(MH, NH, AF, BF) { _Pragma("unroll") for (int mq = 0; mq < 4; ++mq) \
    _Pragma("unroll") for (int nq = 0; nq < 2; ++nq) { \
      f32x4 c = acc[(MH) * 4 + mq][(NH) * 2 + nq]; \
      c = __builtin_amdgcn_mfma_f32_16x16x32_bf16(AF[mq][0], BF[nq][0], c, 0, 0, 0); \
      c = __builtin_amdgcn_mfma_f32_16x16x32_bf16(AF[mq][1], BF[nq][1], c, 0, 0, 0); \
      acc[(MH) * 4 + mq][(NH) * 2 + nq] = c; } }
#define SFENCE() __builtin_amdgcn_sched_barrier(0)

  f32x4 acc[8][4];
#pragma unroll
  for (int i = 0; i < 8; ++i)
#pragma unroll
    for (int j = 0; j < 4; ++j) acc[i][j] = (f32x4){0.f, 0.f, 0.f, 0.f};

  // prologue: stage tiles 0 and 1; tile 0 landed, tile 1 in flight
  STAGE_A(0); STAGE_B(0);
  STAGE_A(1); STAGE_B(1);
  asm volatile("s_waitcnt vmcnt(8)" ::: "memory");
  __builtin_amdgcn_s_barrier();

  bf16x8 a0[4][2], a1[4][2], b0[2][2], b1[2][2];
  RD_A(a0, lds, 0);
  RD_B(b0, ldsB, 0);

#pragma unroll 2
  for (int g = 0; g < 16; ++g) {
    const short* cA = lds + (g & 1) * 16384;
    const short* cB = ldsB + (g & 1) * 16384;
    const short* nA = lds + ((g & 1) ^ 1) * 16384;
    const short* nB = ldsB + ((g & 1) ^ 1) * 16384;

    // P1: issue B1 reads; Q00 waits only for a0/b0 (issued last tile P4)
    RD_B(b1, cB, 1);
    SFENCE();
    __builtin_amdgcn_s_setprio(1); QUAD(0, 0, a0, b0); __builtin_amdgcn_s_setprio(0);
    SFENCE();

    // P2: issue A1 reads; Q01 waits only for b1
    RD_A(a1, cA, 1);
    SFENCE();
    __builtin_amdgcn_s_setprio(1); QUAD(0, 1, a0, b1); __builtin_amdgcn_s_setprio(0);
    SFENCE();

    // P3: barrier = all waves done with B-region of cur buf (b0 drained P1,
    // b1 drained P2, per-wave counted waits precede arrival) -> restage it.
    __builtin_amdgcn_s_barrier();
    if (g <= 13) STAGE_B(g + 2);
    SFENCE();
    __builtin_amdgcn_s_setprio(1); QUAD(1, 0, a1, b0); __builtin_amdgcn_s_setprio(0);
    SFENCE();
    // tile g+1 fully landed (B(g+2)'s 4 loads stay in flight)
    if (g <= 13)      { asm volatile("s_waitcnt vmcnt(4)" ::: "memory"); }
    else if (g == 14) { asm volatile("s_waitcnt vmcnt(0)" ::: "memory"); }

    // P4: barrier publishes buffer g+1 to all waves AND proves A-region of
    // cur buf consumed (a1 drained at Q10). Issue next tile's a0/b0 reads,
    // restage A-region for tile g+2.
    __builtin_amdgcn_s_barrier();
    if (g <= 14) { RD_A(a0, nA, 0); RD_B(b0, nB, 0); }
    if (g <= 13) STAGE_A(g + 2);
    SFENCE();
    __builtin_amdgcn_s_setprio(1); QUAD(1, 1, a1, b1); __builtin_amdgcn_s_setprio(0);
    SFENCE();
  }
#undef STAGE_A
#undef STAGE_B
#undef RD_A
#undef RD_B
#undef QUAD
#undef SFENCE

  float cv = 0.f;
  if (MODE == 2) cv = cvec[ncv0 + z];
  float* ob = out ? out + (size_t)z * o_bs : nullptr;

#pragma unroll
  for (int me = 0; me < 8; ++me) {
#pragma unroll
    for (int ne = 0; ne < 4; ++ne) {
      const int row0 = m0 + wm + me * 16 + q * 4;
      const int col = n0 + wn + ne * 16 + r16;
      f32x4 a = acc[me][ne];
      if (MODE == 1) {
        short4 s;
        s.x = f2bf(a[0]); s.y = f2bf(a[1]); s.z = f2bf(a[2]); s.w = f2bf(a[3]);
        *(short4*)(tout + (size_t)z * t_bs + (size_t)col * 1024 + row0) = s;
      } else {
#pragma unroll
        for (int r = 0; r < 4; ++r) {
          size_t idx = (size_t)(row0 + r) * 1024 + col;
          ob[idx] = a[r] + cv * kB[idx] + bcv[idx];
        }
      }
    }
  }
}

// Fused: abf = bf16(a_cov);  c[n] += sum_ij a_cov[n,i,j]*kA[i,j] + a_mean[n]^T kA a_mean[n]
__global__ __launch_bounds__(256) void conv_acov(const float* __restrict__ a_cov,
                                                 const float* __restrict__ a_mean,
                                                 const float* __restrict__ kA,
                                                 short* __restrict__ abf,
                                                 float* __restrict__ c) {
  const int n = blockIdx.x, ch = blockIdx.y, t = threadIdx.x;
  __shared__ float sm[1024];
  for (int j = t; j < 1024; j += 256) sm[j] = a_mean[n * 1024 + j];
  __syncthreads();
  const float4 amv = ((const float4*)sm)[t];
  const size_t cb = ((size_t)n << 20);
  float acc = 0.f;
  for (int i = ch * 64; i < ch * 64 + 64; ++i) {
    float4 Av = ((const float4*)(kA + ((size_t)i << 10)))[t];
    float4 Cv = ((const float4*)(a_cov + cb + ((size_t)i << 10)))[t];
    short4 s;
    s.x = f2bf(Cv.x); s.y = f2bf(Cv.y); s.z = f2bf(Cv.z); s.w = f2bf(Cv.w);
    *(short4*)(abf + cb + ((size_t)i << 10) + t * 4) = s;
    acc += Av.x * Cv.x + Av.y * Cv.y + Av.z * Cv.z + Av.w * Cv.w;
    acc += sm[i] * (Av.x * amv.x + Av.y * amv.y + Av.z * amv.z + Av.w * amv.w);
  }
#pragma unroll
  for (int off = 32; off > 0; off >>= 1) acc += __shfl_down(acc, off);
  __shared__ float red[4];
  if ((t & 63) == 0) red[t >> 6] = acc;
  __syncthreads();
  if (t == 0) atomicAdd(&c[n], red[0] + red[1] + red[2] + red[3]);
}

// generic f32 -> bf16, float4 granularity; n4 = n/4
__global__ __launch_bounds__(256) void convf(const float* __restrict__ src,
                                             short* __restrict__ dst, int n4) {
  int i = blockIdx.x * 256 + threadIdx.x;
  if (i < n4) {
    float4 v = ((const float4*)src)[i];
    short4 s;
    s.x = f2bf(v.x); s.y = f2bf(v.y); s.z = f2bf(v.z); s.w = f2bf(v.w);
    ((short4*)dst)[i] = s;
  }
}

extern "C" void kernel_launch(void* const* d_in, const int* in_sizes, int n_in,
                              void* d_out, int out_size, void* d_ws, size_t ws_size,
                              hipStream_t stream) {
  const float* a_mean = (const float*)d_in[0];
  const float* a_cov  = (const float*)d_in[1];
  const float* weight = (const float*)d_in[2];
  const float* bias   = (const float*)d_in[3];
  const float* kA     = (const float*)d_in[4];
  const float* kB     = (const float*)d_in[5];
  const float* b_cov  = (const float*)d_in[6];
  float* h_mean = (float*)d_out;
  float* h_cov  = h_mean + (size_t)64 * 1024;

  const size_t SLICE = (size_t)1 << 20;          // elems per batch slice (1024*1024)
  float* cvec = (float*)d_ws;
  short* Wbf  = (short*)((char*)d_ws + 4096);    // 2 MB
  short* ambf = Wbf + SLICE;                     // 128 KB
  char*  p    = (char*)(ambf + 65536);
  const size_t need_big = (size_t)((char*)p - (char*)d_ws) + 4 * SLICE * 64; // abf + Tt
  const bool big = ws_size >= need_big;

  short* abf, *Tt;
  if (big) {
    abf = (short*)p;
    Tt  = abf + 64 * SLICE;
  } else {
    abf = (short*)h_cov;                         // lower 128 MB of h_cov region
    Tt  = (short*)(h_cov + 64 * SLICE / 2);      // upper 128 MB
  }

  // one-time opt-in to 128 KiB dynamic LDS for the 256^2 kernels
  static int use256 = -1;
  if (use256 < 0) {
    auto k1 = gemm256<1>;
    auto k2 = gemm256<2>;
    bool ok1 = hipFuncSetAttribute(reinterpret_cast<const void*>(k1),
                                   hipFuncAttributeMaxDynamicSharedMemorySize, 131072) == hipSuccess;
    bool ok2 = hipFuncSetAttribute(reinterpret_cast<const void*>(k2),
                                   hipFuncAttributeMaxDynamicSharedMemorySize, 131072) == hipSuccess;
    use256 = (ok1 && ok2) ? 1 : 0;
  }

  hipMemsetAsync(cvec, 0, 64 * sizeof(float), stream);
  convf<<<dim3(1024), 256, 0, stream>>>(weight, Wbf, 262144);
  convf<<<dim3(64), 256, 0, stream>>>(a_mean, ambf, 16384);
  conv_acov<<<dim3(64, 16), 256, 0, stream>>>(a_cov, a_mean, kA, abf, cvec);

  // pass 1: Tt[n][l,i] = bf16( (a_cov[n] @ W^T)[i,l] )
  if (use256) {
    gemm256<1><<<dim3(4, 4, 64), 512, 131072, stream>>>(
        abf, SLICE, Wbf, 0, nullptr, 0, Tt, SLICE,
        nullptr, nullptr, nullptr, 0);
  } else {
    gemm_bt<1><<<dim3(8, 8, 64), 256, 0, stream>>>(
        abf, SLICE, Wbf, 0, nullptr, 0, Tt, SLICE,
        nullptr, nullptr, nullptr, 0, nullptr, 1024);
  }

  // h_mean = a_mean @ W^T + bias (M=64, clamped rows + guarded store)
  gemm_bt<0><<<dim3(8, 1, 1), 256, 0, stream>>>(
      ambf, 0, Wbf, 0, h_mean, 0, nullptr, 0,
      nullptr, nullptr, nullptr, 0, bias, 64);

  if (big) {
    // pass 2: h_cov[n] = W @ T[n] + c[n]*kB + b_cov
    if (use256) {
      gemm256<2><<<dim3(4, 4, 64), 512, 131072, stream>>>(
          Wbf, 0, Tt, SLICE, h_cov, SLICE, nullptr, 0,
          kB, b_cov, cvec, 0);
    } else {
      gemm_bt<2><<<dim3(8, 8, 64), 256, 0, stream>>>(
          Wbf, 0, Tt, SLICE, h_cov, SLICE, nullptr, 0,
          kB, b_cov, cvec, 0, nullptr, 1024);
    }
  } else {
    // In-place: h_cov[n] write clobbers Tt[m], m in {2n-64, 2n-63}.
    // Increasing windows keep clobbered m strictly below the window start.
    short* T63 = ambf + 65536;                   // 2 MB scratch in ws
    hipMemcpyAsync(T63, Tt + 63 * SLICE, SLICE * 2, hipMemcpyDeviceToDevice, stream);
    const int st[6] = {0, 32, 48, 56, 60, 62};
    const int ln[6] = {32, 16, 8, 4, 2, 1};
    for (int w = 0; w < 6; ++w) {
      if (use256) {
        gemm256<2><<<dim3(4, 4, ln[w]), 512, 131072, stream>>>(
            Wbf, 0, Tt + (size_t)st[w] * SLICE, SLICE,
            h_cov + (size_t)st[w] * SLICE, SLICE, nullptr, 0,
            kB, b_cov, cvec, st[w]);
      } else {
        gemm_bt<2><<<dim3(8, 8, ln[w]), 256, 0, stream>>>(
            Wbf, 0, Tt + (size_t)st[w] * SLICE, SLICE,
            h_cov + (size_t)st[w] * SLICE, SLICE, nullptr, 0,
            kB, b_cov, cvec, st[w], nullptr, 1024);
      }
    }
    if (use256) {
      gemm256<2><<<dim3(4, 4, 1), 512, 131072, stream>>>(
          Wbf, 0, T63, 0, h_cov + (size_t)63 * SLICE, 0, nullptr, 0,
          kB, b_cov, cvec, 63);
    } else {
      gemm_bt<2><<<dim3(8, 8, 1), 256, 0, stream>>>(
          Wbf, 0, T63, 0, h_cov + (size_t)63 * SLICE, 0, nullptr, 0,
          kB, b_cov, cvec, 63, nullptr, 1024);
    }
  }
}